// Round 7
// baseline (2332.684 us; speedup 1.0000x reference)
//
#include <hip/hip_runtime.h>
#include <hip/hip_bf16.h>
#include <hip/hip_cooperative_groups.h>

namespace cg = cooperative_groups;

constexpr int B = 512;
constexpr int I = 512;
constexpr int H = 1024;
constexpr int O = 512;

using short8 = __attribute__((ext_vector_type(8))) short;
using f32x4  = __attribute__((ext_vector_type(4))) float;
using bf16_t = __hip_bfloat16;

__device__ __forceinline__ short8 ldfrag(const bf16_t* p) {
    return *reinterpret_cast<const short8*>(p);
}
__device__ __forceinline__ float sigmoid_f(float z) {
    return 1.0f / (1.0f + __expf(-z));
}

// ---- RMW-free group barrier, agent-scope flags (R3 skeleton, FROZEN) ----
// Evidence log:
//  R0/R2/R3 pass (absmax 0.015625) with this h data path: plain stores to the
//   co-XCD L2, __syncthreads drain, agent-scope flag, L1-only invalidate.
//  R4 (flag-granularity streaming) and R5 (bulk register-prefetch k-loop)
//   BOTH corrupt h despite provably identical math => the gate-loop load
//   schedule + barrier code below is frozen; only work outside it may move.
//  R2 calibrated flag detection latency at <<1us (not the bottleneck).
//  R6 = this exact kernel; infra failed twice (no signal). Audited for
//   deadlock vectors vs R3: none (barrier byte-identical, slack block has no
//   sync, ring slot-2 first write gated by group_wait(1) after all jx/kx
//   reads). Resubmitting unchanged.
// Change under test (outside the frozen path): remove the has_out asymmetry
// from the barrier-gated critical path. 32/64 WGs per group ran ~50% heavier
// gate loops (Wo loads + accO MFMA + out stores); the barrier runs every step
// at the max over 64 WGs. Now ALL WGs run identical minimal gate loops;
// accO/out happen AFTER group_post, overlapped with straggler wait. h ring
// deepened 2->3 (3rd slot aliases dead wjx_bf) so h_t stays readable after
// posting t+1: nobody overwrites ring[t%3] until all WGs post t+2, and our
// post(t+2) is program-ordered after our slack-accO(t).
__device__ __forceinline__ void group_wait(const int* flags, int target) {
    if (threadIdx.x < 64) {
        const int* p = flags + threadIdx.x * 4;      // 16B-spaced slots
        while (__hip_atomic_load(p, __ATOMIC_RELAXED, __HIP_MEMORY_SCOPE_AGENT) < target)
            __builtin_amdgcn_s_sleep(1);
    }
    __syncthreads();
    asm volatile("buffer_inv sc0" ::: "memory");     // L1-only invalidate
}

__device__ __forceinline__ void group_post(int* flags, int lblk, int value) {
    __syncthreads();  // drains this WG's h stores to local L2 (vmcnt 0)
    if (threadIdx.x == 0)
        __hip_atomic_store(flags + lblk * 4, value,
                           __ATOMIC_RELAXED, __HIP_MEMORY_SCOPE_AGENT);
}

// 512 WGs x 256 thr, 64KB LDS (Wjh+Wkh slices), 2 WGs/CU.
// WG(g): iblk = g&7 (64 batch rows, XCD-local group), lblk = g>>3 (16 gate cols).
// lblk<32 WGs additionally compute 16 out cols (in post-barrier slack).
__global__ __launch_bounds__(256, 2)
void flipflop_rnn_kernel(const float* __restrict__ x,  const float* __restrict__ h0,
                         const float* __restrict__ Wjx, const float* __restrict__ bjx,
                         const float* __restrict__ Wjh, const float* __restrict__ bjh,
                         const float* __restrict__ Wkx, const float* __restrict__ bkx,
                         const float* __restrict__ Wkh, const float* __restrict__ bkh,
                         const float* __restrict__ Wo,  const float* __restrict__ bo,
                         const int* __restrict__ seqlen,
                         float* __restrict__ out,
                         bf16_t* __restrict__ wjh_bf, bf16_t* __restrict__ wkh_bf,
                         bf16_t* __restrict__ wo_bf,  bf16_t* __restrict__ wjx_bf,
                         bf16_t* __restrict__ wkx_bf, bf16_t* __restrict__ x_bf,
                         bf16_t* __restrict__ hbf0,   bf16_t* __restrict__ hbf1,
                         int* __restrict__ cnt)
{
    // [gate][kb 0..127][col 0..15][8 shorts] = 65536 B
    __shared__ short lds_w[32768];

    const int T    = seqlen[0];
    const int tid  = threadIdx.x;
    const int g    = blockIdx.x;
    const int nthr = gridDim.x * blockDim.x;
    const int gtid = g * blockDim.x + tid;

    // ---- cast weights & x to bf16; zero barrier flags ----
    for (int idx = gtid; idx < H * H; idx += nthr) wjh_bf[idx] = __float2bfloat16(Wjh[idx]);
    for (int idx = gtid; idx < H * H; idx += nthr) wkh_bf[idx] = __float2bfloat16(Wkh[idx]);
    for (int idx = gtid; idx < O * H; idx += nthr) wo_bf[idx]  = __float2bfloat16(Wo[idx]);
    for (int idx = gtid; idx < H * I; idx += nthr) wjx_bf[idx] = __float2bfloat16(Wjx[idx]);
    for (int idx = gtid; idx < H * I; idx += nthr) wkx_bf[idx] = __float2bfloat16(Wkx[idx]);
    for (int idx = gtid; idx < B * I; idx += nthr) x_bf[idx]   = __float2bfloat16(x[idx]);
    if (gtid < 8 * 256) cnt[gtid] = 0;   // 8 groups x 64 flags x 16B spacing

    // ---- geometry ----
    const int w     = tid >> 6;
    const int lane  = tid & 63;
    const int quad  = lane >> 4;
    const int lm    = lane & 15;
    const int iblk  = g & 7;
    const int lblk  = g >> 3;           // 0..63
    const int rbase = iblk * 64 + w * 16;
    const int n0    = lblk * 16;        // gate cols
    const bool has_out = (lblk < 32);
    const int no0   = lblk * 16;        // out cols (valid when has_out)
    int* grp_flags = cnt + iblk * 256;

    // ---- h0 init ----
    float hreg[4];
    #pragma unroll
    for (int r = 0; r < 4; ++r) {
        const int row = rbase + quad * 4 + r;
        const int col = n0 + lm;
        const float hv = h0[row * H + col];
        hreg[r] = hv;
        hbf0[row * H + col] = __float2bfloat16(hv);
    }

    cg::this_grid().sync();   // casts + h0 + flag zeros visible device-wide

    // ---- Wjh/Wkh slices -> LDS (once) ----
    for (int c = tid; c < 4096; c += 256) {
        const int gate = c >> 11;
        const int cc   = c & 2047;
        const int kb   = cc >> 4;
        const int col  = cc & 15;
        const bf16_t* src = (gate ? wkh_bf : wjh_bf) + (n0 + col) * H + kb * 8;
        *reinterpret_cast<short8*>(&lds_w[c * 8]) = *reinterpret_cast<const short8*>(src);
    }
    __syncthreads();

    // ---- jx/kx (+ all biases) in registers ----
    float jxr[4], kxr[4];
    {
        f32x4 aJ = {0.f, 0.f, 0.f, 0.f};
        f32x4 aK = {0.f, 0.f, 0.f, 0.f};
        const bf16_t* aP = x_bf   + (rbase + lm) * I + quad * 8;
        const bf16_t* jP = wjx_bf + (n0 + lm) * I + quad * 8;
        const bf16_t* kP = wkx_bf + (n0 + lm) * I + quad * 8;
        #pragma unroll 4
        for (int k0 = 0; k0 < I; k0 += 32) {
            short8 a = ldfrag(aP + k0);
            aJ = __builtin_amdgcn_mfma_f32_16x16x32_bf16(a, ldfrag(jP + k0), aJ, 0, 0, 0);
            aK = __builtin_amdgcn_mfma_f32_16x16x32_bf16(a, ldfrag(kP + k0), aK, 0, 0, 0);
        }
        const int col = n0 + lm;
        #pragma unroll
        for (int r = 0; r < 4; ++r) {
            jxr[r] = aJ[r] + bjx[col] + bjh[col];
            kxr[r] = aK[r] + bkx[col] + bkh[col];
        }
    }
    const float bo_v = has_out ? bo[no0 + lm] : 0.0f;

    // ---- 3-deep h ring: slot2 reuses wjx_bf (dead after jx/kx; first write
    // is at t=1's update, gated by group_wait(1) => ordered after every WG's
    // jx/kx reads). Rotating pointers keep indices compile-time static.
    const bf16_t* h_r = hbf0;                 // ring[t%3]     (read)
    bf16_t*       h_w = hbf1;                 // ring[(t+1)%3] (write)
    bf16_t*       h_n = (bf16_t*)wjx_bf;      // ring[(t+2)%3] (next)

    // ---- recurrence: step t reads h_t, computes h_{t+1}; out_{t-1} in slack ----
    for (int t = 0; t < T; ++t) {
        if (t > 0) group_wait(grp_flags, t);

        f32x4 accJ = {0.f, 0.f, 0.f, 0.f};
        f32x4 accK = {0.f, 0.f, 0.f, 0.f};

        const bf16_t* aP = h_r + (rbase + lm) * H + quad * 8;
        const short*  jL = lds_w + quad * 128 + lm * 8;          // [kb][col][8]
        const short*  kL = jL + 16384;

        // minimal, symmetric gate loop (FROZEN schedule: R3's else-branch)
        #pragma unroll 4
        for (int k0 = 0; k0 < H; k0 += 32) {
            short8 a  = ldfrag(aP + k0);
            short8 bj = *reinterpret_cast<const short8*>(jL + (k0 >> 3) * 128);
            short8 bk = *reinterpret_cast<const short8*>(kL + (k0 >> 3) * 128);
            accJ = __builtin_amdgcn_mfma_f32_16x16x32_bf16(a, bj, accJ, 0, 0, 0);
            accK = __builtin_amdgcn_mfma_f32_16x16x32_bf16(a, bk, accK, 0, 0, 0);
        }

        // h update + publish (group critical path)
        #pragma unroll
        for (int r = 0; r < 4; ++r) {
            const int row = rbase + quad * 4 + r;
            const int col = n0 + lm;
            const float jv = sigmoid_f(accJ[r] + jxr[r]);
            const float kv = sigmoid_f(accK[r] + kxr[r]);
            const float hv = hreg[r];
            const float hn = jv * (1.0f - hv) + (1.0f - kv) * hv;
            hreg[r] = hn;
            h_w[row * H + col] = __float2bfloat16(hn);
        }

        group_post(grp_flags, lblk, t + 1);   // publish h_{t+1}

        // ---- slack work: out_{t-1} = h_t @ Wo^T (overlaps straggler wait).
        // h_t (h_r) stays valid: ring[t%3] is only rewritten at step t+2's
        // update, gated on ALL flags >= t+2, and our post(t+2) is program-
        // ordered after this block. A-lines are L1-warm from the gate loop.
        if (has_out && t > 0) {
            f32x4 accO = {0.f, 0.f, 0.f, 0.f};
            const bf16_t* oP = wo_bf + (no0 + lm) * H + quad * 8;
            #pragma unroll 4
            for (int k0 = 0; k0 < H; k0 += 32) {
                accO = __builtin_amdgcn_mfma_f32_16x16x32_bf16(
                    ldfrag(aP + k0), ldfrag(oP + k0), accO, 0, 0, 0);
            }
            #pragma unroll
            for (int r = 0; r < 4; ++r) {
                const int row = rbase + quad * 4 + r;
                out[(row * T + (t - 1)) * O + no0 + lm] = accO[r] + bo_v;
            }
        }

        // rotate ring
        const bf16_t* tmp = h_r;
        h_r = h_w;
        h_w = h_n;
        h_n = (bf16_t*)tmp;
    }

    group_wait(grp_flags, T);       // h_T published; h_r == ring[T%3] == h_T

    // ---- epilogue: out_{T-1} and h_final ----
    {
        if (has_out) {
            f32x4 accO = {0.f, 0.f, 0.f, 0.f};
            const bf16_t* aP = h_r   + (rbase + lm) * H + quad * 8;
            const bf16_t* oP = wo_bf + (no0 + lm) * H + quad * 8;
            #pragma unroll 4
            for (int k0 = 0; k0 < H; k0 += 32) {
                accO = __builtin_amdgcn_mfma_f32_16x16x32_bf16(ldfrag(aP + k0), ldfrag(oP + k0), accO, 0, 0, 0);
            }
            #pragma unroll
            for (int r = 0; r < 4; ++r) {
                const int row = rbase + quad * 4 + r;
                out[(row * T + (T - 1)) * O + no0 + lm] = accO[r] + bo_v;
            }
        }
        const int hfin = B * T * O;
        #pragma unroll
        for (int r = 0; r < 4; ++r) {
            const int row = rbase + quad * 4 + r;
            const int col = n0 + lm;
            out[hfin + row * H + col] = hreg[r];
        }
    }
}

extern "C" void kernel_launch(void* const* d_in, const int* in_sizes, int n_in,
                              void* d_out, int out_size, void* d_ws, size_t ws_size,
                              hipStream_t stream) {
    const float* x   = (const float*)d_in[0];
    const float* h0  = (const float*)d_in[1];
    const float* Wjx = (const float*)d_in[2];
    const float* bjx = (const float*)d_in[3];
    const float* Wjh = (const float*)d_in[4];
    const float* bjh = (const float*)d_in[5];
    const float* Wkx = (const float*)d_in[6];
    const float* bkx = (const float*)d_in[7];
    const float* Wkh = (const float*)d_in[8];
    const float* bkh = (const float*)d_in[9];
    const float* Wo  = (const float*)d_in[10];
    const float* bo  = (const float*)d_in[11];
    const int* seqlen = (const int*)d_in[12];
    float* out = (float*)d_out;

    // workspace layout (bytes)
    char* ws = (char*)d_ws;
    bf16_t* wjh_bf = (bf16_t*)(ws + 0);                 // 2 MB
    bf16_t* wkh_bf = (bf16_t*)(ws + 2097152);           // 2 MB
    bf16_t* wo_bf  = (bf16_t*)(ws + 4194304);           // 1 MB
    bf16_t* wjx_bf = (bf16_t*)(ws + 5242880);           // 1 MB (ring slot 2 after init)
    bf16_t* wkx_bf = (bf16_t*)(ws + 6291456);           // 1 MB
    bf16_t* x_bf   = (bf16_t*)(ws + 7340032);           // 0.5 MB
    bf16_t* hbf0   = (bf16_t*)(ws + 7864320);           // 1 MB (ring slot 0)
    bf16_t* hbf1   = (bf16_t*)(ws + 8912896);           // 1 MB (ring slot 1)
    int*    cnt    = (int*)   (ws + 9961472);           // 8 KB barrier flags

    void* args[] = {
        &x, &h0, &Wjx, &bjx, &Wjh, &bjh, &Wkx, &bkx, &Wkh, &bkh, &Wo, &bo,
        &seqlen, &out,
        &wjh_bf, &wkh_bf, &wo_bf, &wjx_bf, &wkx_bf, &x_bf, &hbf0, &hbf1, &cnt
    };
    hipLaunchCooperativeKernel((const void*)flipflop_rnn_kernel,
                               dim3(512), dim3(256), args, 0, stream);
}

// Round 8
// 2043.655 us; speedup vs baseline: 1.1414x; 1.1414x over previous
//
#include <hip/hip_runtime.h>
#include <hip/hip_bf16.h>
#include <hip/hip_cooperative_groups.h>

namespace cg = cooperative_groups;

constexpr int B = 512;
constexpr int I = 512;
constexpr int H = 1024;
constexpr int O = 512;

using short8 = __attribute__((ext_vector_type(8))) short;
using f32x4  = __attribute__((ext_vector_type(4))) float;
using bf16_t = __hip_bfloat16;

__device__ __forceinline__ short8 ldfrag(const bf16_t* p) {
    return *reinterpret_cast<const short8*>(p);
}
__device__ __forceinline__ float sigmoid_f(float z) {
    return 1.0f / (1.0f + __expf(-z));
}

// ---- R0 barrier, verbatim (best-measured: 1890us) ----
// Evidence log (8 rounds): R0=1890 (this structure), R3 flag-barrier=2044,
// R7 slack-Wo=2256. Every "move work after the post" change made it SLOWER;
// MfmaUtil/VALUBusy ~6-7% throughout => step period ~= per-WG stalled-load
// time, NOT barrier mechanics (three barrier designs within 15%), NOT
// critical-path-into-post. R4/R5's restructured load schedules corrupted h =>
// only R0/R3-shaped loops are trusted. This round: exact R0 + ONE change:
// gate-loop unroll 4->8 (halves serialized vmcnt windows per pass; probes the
// contended-window-latency theory against the best-known baseline).
__device__ __forceinline__ void group_wait(int* c, int target) {
    if (threadIdx.x == 0) {
        while (__hip_atomic_load(c, __ATOMIC_RELAXED, __HIP_MEMORY_SCOPE_AGENT) < target)
            __builtin_amdgcn_s_sleep(2);
    }
    __syncthreads();
    asm volatile("buffer_inv sc0" ::: "memory");   // L1-only invalidate
}
__device__ __forceinline__ void group_post(int* c) {
    __syncthreads();  // drains this WG's h stores to local L2 (vmcnt 0)
    if (threadIdx.x == 0)
        __hip_atomic_fetch_add(c, 1, __ATOMIC_RELAXED, __HIP_MEMORY_SCOPE_AGENT);
}

// 512 WGs x 256 thr, 64KB LDS (Wjh+Wkh slices), 2 WGs/CU.
// WG(g): iblk = g&7 (64 batch rows, XCD-local group), lblk = g>>3 (16 gate cols).
// lblk<32 WGs additionally compute 16 out cols (Wo streamed from L2).
__global__ __launch_bounds__(256, 2)
void flipflop_rnn_kernel(const float* __restrict__ x,  const float* __restrict__ h0,
                         const float* __restrict__ Wjx, const float* __restrict__ bjx,
                         const float* __restrict__ Wjh, const float* __restrict__ bjh,
                         const float* __restrict__ Wkx, const float* __restrict__ bkx,
                         const float* __restrict__ Wkh, const float* __restrict__ bkh,
                         const float* __restrict__ Wo,  const float* __restrict__ bo,
                         const int* __restrict__ seqlen,
                         float* __restrict__ out,
                         bf16_t* __restrict__ wjh_bf, bf16_t* __restrict__ wkh_bf,
                         bf16_t* __restrict__ wo_bf,  bf16_t* __restrict__ wjx_bf,
                         bf16_t* __restrict__ wkx_bf, bf16_t* __restrict__ x_bf,
                         bf16_t* __restrict__ hbf0,   bf16_t* __restrict__ hbf1,
                         int* __restrict__ cnt)
{
    // [gate][kb 0..127][col 0..15][8 shorts] = 65536 B
    __shared__ short lds_w[32768];

    const int T    = seqlen[0];
    const int tid  = threadIdx.x;
    const int g    = blockIdx.x;
    const int nthr = gridDim.x * blockDim.x;
    const int gtid = g * blockDim.x + tid;

    // ---- cast weights & x to bf16; zero barrier counters ----
    for (int idx = gtid; idx < H * H; idx += nthr) wjh_bf[idx] = __float2bfloat16(Wjh[idx]);
    for (int idx = gtid; idx < H * H; idx += nthr) wkh_bf[idx] = __float2bfloat16(Wkh[idx]);
    for (int idx = gtid; idx < O * H; idx += nthr) wo_bf[idx]  = __float2bfloat16(Wo[idx]);
    for (int idx = gtid; idx < H * I; idx += nthr) wjx_bf[idx] = __float2bfloat16(Wjx[idx]);
    for (int idx = gtid; idx < H * I; idx += nthr) wkx_bf[idx] = __float2bfloat16(Wkx[idx]);
    for (int idx = gtid; idx < B * I; idx += nthr) x_bf[idx]   = __float2bfloat16(x[idx]);
    if (gtid < 8 * 256) cnt[gtid] = 0;

    // ---- geometry ----
    const int w     = tid >> 6;
    const int lane  = tid & 63;
    const int quad  = lane >> 4;
    const int lm    = lane & 15;
    const int iblk  = g & 7;            // XCD-local group id
    const int lblk  = g >> 3;           // 0..63
    const int rbase = iblk * 64 + w * 16;
    const int n0    = lblk * 16;        // gate cols
    const bool has_out = (lblk < 32);
    const int no0   = lblk * 16;        // out cols (valid when has_out)
    int* grp_cnt = cnt + iblk * 256;

    // ---- h0 init: each thread owns 4 (row,col) elements ----
    float hreg[4];
    #pragma unroll
    for (int r = 0; r < 4; ++r) {
        const int row = rbase + quad * 4 + r;
        const int col = n0 + lm;
        const float hv = h0[row * H + col];
        hreg[r] = hv;
        hbf0[row * H + col] = __float2bfloat16(hv);
    }

    cg::this_grid().sync();   // casts + h0 + cnt zero visible device-wide

    // ---- load this WG's Wjh/Wkh rows into LDS (one time) ----
    for (int c = tid; c < 4096; c += 256) {
        const int gate = c >> 11;
        const int cc   = c & 2047;
        const int kb   = cc >> 4;
        const int col  = cc & 15;
        const bf16_t* src = (gate ? wkh_bf : wjh_bf) + (n0 + col) * H + kb * 8;
        *reinterpret_cast<short8*>(&lds_w[c * 8]) = *reinterpret_cast<const short8*>(src);
    }
    __syncthreads();

    // ---- jx/kx (+ all biases) in registers ----
    float jxr[4], kxr[4];
    {
        f32x4 aJ = {0.f, 0.f, 0.f, 0.f};
        f32x4 aK = {0.f, 0.f, 0.f, 0.f};
        const bf16_t* aP = x_bf   + (rbase + lm) * I + quad * 8;
        const bf16_t* jP = wjx_bf + (n0 + lm) * I + quad * 8;
        const bf16_t* kP = wkx_bf + (n0 + lm) * I + quad * 8;
        #pragma unroll 4
        for (int k0 = 0; k0 < I; k0 += 32) {
            short8 a = ldfrag(aP + k0);
            aJ = __builtin_amdgcn_mfma_f32_16x16x32_bf16(a, ldfrag(jP + k0), aJ, 0, 0, 0);
            aK = __builtin_amdgcn_mfma_f32_16x16x32_bf16(a, ldfrag(kP + k0), aK, 0, 0, 0);
        }
        const int col = n0 + lm;
        #pragma unroll
        for (int r = 0; r < 4; ++r) {
            jxr[r] = aJ[r] + bjx[col] + bjh[col];
            kxr[r] = aK[r] + bkx[col] + bkh[col];
        }
    }
    const float bo_v = has_out ? bo[no0 + lm] : 0.0f;

    // ---- recurrence: step t reads h_t, computes h_{t+1} and out_{t-1} ----
    for (int t = 0; t < T; ++t) {
        if (t > 0) group_wait(grp_cnt + t, 64);   // h_t published by all 64 group WGs
        const bf16_t* hb  = (t & 1) ? hbf1 : hbf0;
        bf16_t*       hbn = (t & 1) ? hbf0 : hbf1;

        f32x4 accJ = {0.f, 0.f, 0.f, 0.f};
        f32x4 accK = {0.f, 0.f, 0.f, 0.f};
        f32x4 accO = {0.f, 0.f, 0.f, 0.f};

        const bf16_t* aP = hb    + (rbase + lm) * H + quad * 8;
        const bf16_t* oP = wo_bf + (no0 + lm) * H + quad * 8;
        const short*  jL = lds_w + quad * 128 + lm * 8;          // [kb][col][8]
        const short*  kL = jL + 16384;

        if (has_out) {
            #pragma unroll 8
            for (int k0 = 0; k0 < H; k0 += 32) {
                short8 a  = ldfrag(aP + k0);
                short8 bj = *reinterpret_cast<const short8*>(jL + (k0 >> 3) * 128);
                short8 bk = *reinterpret_cast<const short8*>(kL + (k0 >> 3) * 128);
                accJ = __builtin_amdgcn_mfma_f32_16x16x32_bf16(a, bj, accJ, 0, 0, 0);
                accK = __builtin_amdgcn_mfma_f32_16x16x32_bf16(a, bk, accK, 0, 0, 0);
                accO = __builtin_amdgcn_mfma_f32_16x16x32_bf16(a, ldfrag(oP + k0), accO, 0, 0, 0);
            }
        } else {
            #pragma unroll 8
            for (int k0 = 0; k0 < H; k0 += 32) {
                short8 a  = ldfrag(aP + k0);
                short8 bj = *reinterpret_cast<const short8*>(jL + (k0 >> 3) * 128);
                short8 bk = *reinterpret_cast<const short8*>(kL + (k0 >> 3) * 128);
                accJ = __builtin_amdgcn_mfma_f32_16x16x32_bf16(a, bj, accJ, 0, 0, 0);
                accK = __builtin_amdgcn_mfma_f32_16x16x32_bf16(a, bk, accK, 0, 0, 0);
            }
        }

        if (has_out && t > 0) {
            #pragma unroll
            for (int r = 0; r < 4; ++r) {
                const int row = rbase + quad * 4 + r;
                out[(row * T + (t - 1)) * O + no0 + lm] = accO[r] + bo_v;
            }
        }

        #pragma unroll
        for (int r = 0; r < 4; ++r) {
            const int row = rbase + quad * 4 + r;
            const int col = n0 + lm;
            const float jv = sigmoid_f(accJ[r] + jxr[r]);
            const float kv = sigmoid_f(accK[r] + kxr[r]);
            const float hv = hreg[r];
            const float hn = jv * (1.0f - hv) + (1.0f - kv) * hv;
            hreg[r] = hn;
            hbn[row * H + col] = __float2bfloat16(hn);
        }

        group_post(grp_cnt + t + 1);   // publish h_{t+1}
    }

    group_wait(grp_cnt + T, 64);       // h_T published

    // ---- epilogue: out_{T-1} and h_final ----
    {
        const bf16_t* hb = (T & 1) ? hbf1 : hbf0;
        if (has_out) {
            f32x4 accO = {0.f, 0.f, 0.f, 0.f};
            const bf16_t* aP = hb    + (rbase + lm) * H + quad * 8;
            const bf16_t* oP = wo_bf + (no0 + lm) * H + quad * 8;
            #pragma unroll 4
            for (int k0 = 0; k0 < H; k0 += 32) {
                accO = __builtin_amdgcn_mfma_f32_16x16x32_bf16(ldfrag(aP + k0), ldfrag(oP + k0), accO, 0, 0, 0);
            }
            #pragma unroll
            for (int r = 0; r < 4; ++r) {
                const int row = rbase + quad * 4 + r;
                out[(row * T + (T - 1)) * O + no0 + lm] = accO[r] + bo_v;
            }
        }
        const int hfin = B * T * O;
        #pragma unroll
        for (int r = 0; r < 4; ++r) {
            const int row = rbase + quad * 4 + r;
            const int col = n0 + lm;
            out[hfin + row * H + col] = hreg[r];
        }
    }
}

extern "C" void kernel_launch(void* const* d_in, const int* in_sizes, int n_in,
                              void* d_out, int out_size, void* d_ws, size_t ws_size,
                              hipStream_t stream) {
    const float* x   = (const float*)d_in[0];
    const float* h0  = (const float*)d_in[1];
    const float* Wjx = (const float*)d_in[2];
    const float* bjx = (const float*)d_in[3];
    const float* Wjh = (const float*)d_in[4];
    const float* bjh = (const float*)d_in[5];
    const float* Wkx = (const float*)d_in[6];
    const float* bkx = (const float*)d_in[7];
    const float* Wkh = (const float*)d_in[8];
    const float* bkh = (const float*)d_in[9];
    const float* Wo  = (const float*)d_in[10];
    const float* bo  = (const float*)d_in[11];
    const int* seqlen = (const int*)d_in[12];
    float* out = (float*)d_out;

    // workspace layout (bytes)
    char* ws = (char*)d_ws;
    bf16_t* wjh_bf = (bf16_t*)(ws + 0);                 // 2 MB
    bf16_t* wkh_bf = (bf16_t*)(ws + 2097152);           // 2 MB
    bf16_t* wo_bf  = (bf16_t*)(ws + 4194304);           // 1 MB
    bf16_t* wjx_bf = (bf16_t*)(ws + 5242880);           // 1 MB
    bf16_t* wkx_bf = (bf16_t*)(ws + 6291456);           // 1 MB
    bf16_t* x_bf   = (bf16_t*)(ws + 7340032);           // 0.5 MB
    bf16_t* hbf0   = (bf16_t*)(ws + 7864320);           // 1 MB
    bf16_t* hbf1   = (bf16_t*)(ws + 8912896);           // 1 MB
    int*    cnt    = (int*)   (ws + 9961472);           // 8 KB barrier counters

    void* args[] = {
        &x, &h0, &Wjx, &bjx, &Wjh, &bjh, &Wkx, &bkx, &Wkh, &bkh, &Wo, &bo,
        &seqlen, &out,
        &wjh_bf, &wkh_bf, &wo_bf, &wjx_bf, &wkx_bf, &x_bf, &hbf0, &hbf1, &cnt
    };
    hipLaunchCooperativeKernel((const void*)flipflop_rnn_kernel,
                               dim3(512), dim3(256), args, 0, stream);
}

// Round 9
// 2026.262 us; speedup vs baseline: 1.1512x; 1.0086x over previous
//
#include <hip/hip_runtime.h>
#include <hip/hip_bf16.h>
#include <hip/hip_cooperative_groups.h>

namespace cg = cooperative_groups;

constexpr int B = 512;
constexpr int I = 512;
constexpr int H = 1024;
constexpr int O = 512;

using short8 = __attribute__((ext_vector_type(8))) short;
using f32x4  = __attribute__((ext_vector_type(4))) float;
using bf16_t = __hip_bfloat16;

__device__ __forceinline__ short8 ldfrag(const bf16_t* p) {
    return *reinterpret_cast<const short8*>(p);
}
__device__ __forceinline__ float sigmoid_f(float z) {
    return 1.0f / (1.0f + __expf(-z));
}

// ---- R0 barrier with ONE change: buffer_inv sc0 -> plain buffer_inv ----
// Evidence log (9 rounds): step time ~15us INVARIANT under 3 barrier designs
// (R0 fetch_add / R3 spread flags / R2 dual-scope), work placement (R7), and
// unroll depth (R8). Issue counters ~1-2us/step; arithmetic says local-L2
// serviced loads would give ~5us steps => k-loop loads are being serviced at
// MALL-class latency. The one instruction present in EVERY round:
// `buffer_inv sc0`. On gfx940+ the sc bits encode SCOPE; on a multi-XCD part
// an agent-scope invalidate plausibly nukes L1 AND the XCD L2 (agent
// coherence point = MALL). 64 WGs x 128 steps of full-L2 invalidation =>
// every h/Wo read refetches from MALL => the invariant 15us.
// Plain `buffer_inv` (sc bits 0 = CU scope) is GUARANTEED L1-only:
// correctness identical (consumer L1 inv'd; producer stores are in the
// shared co-XCD L2 via write-through L1 + syncthreads vmcnt drain -- the
// exact data path proven in R0/R2/R3/R7/R8), but the L2 survives.
__device__ __forceinline__ void group_wait(int* c, int target) {
    if (threadIdx.x == 0) {
        while (__hip_atomic_load(c, __ATOMIC_RELAXED, __HIP_MEMORY_SCOPE_AGENT) < target)
            __builtin_amdgcn_s_sleep(2);
    }
    __syncthreads();
    asm volatile("buffer_inv" ::: "memory");   // CU-scope: L1-only invalidate
}
__device__ __forceinline__ void group_post(int* c) {
    __syncthreads();  // drains this WG's h stores to local L2 (vmcnt 0)
    if (threadIdx.x == 0)
        __hip_atomic_fetch_add(c, 1, __ATOMIC_RELAXED, __HIP_MEMORY_SCOPE_AGENT);
}

// 512 WGs x 256 thr, 64KB LDS (Wjh+Wkh slices), 2 WGs/CU.
// WG(g): iblk = g&7 (64 batch rows, XCD-local group), lblk = g>>3 (16 gate cols).
// lblk<32 WGs additionally compute 16 out cols (Wo streamed from L2).
__global__ __launch_bounds__(256, 2)
void flipflop_rnn_kernel(const float* __restrict__ x,  const float* __restrict__ h0,
                         const float* __restrict__ Wjx, const float* __restrict__ bjx,
                         const float* __restrict__ Wjh, const float* __restrict__ bjh,
                         const float* __restrict__ Wkx, const float* __restrict__ bkx,
                         const float* __restrict__ Wkh, const float* __restrict__ bkh,
                         const float* __restrict__ Wo,  const float* __restrict__ bo,
                         const int* __restrict__ seqlen,
                         float* __restrict__ out,
                         bf16_t* __restrict__ wjh_bf, bf16_t* __restrict__ wkh_bf,
                         bf16_t* __restrict__ wo_bf,  bf16_t* __restrict__ wjx_bf,
                         bf16_t* __restrict__ wkx_bf, bf16_t* __restrict__ x_bf,
                         bf16_t* __restrict__ hbf0,   bf16_t* __restrict__ hbf1,
                         int* __restrict__ cnt)
{
    // [gate][kb 0..127][col 0..15][8 shorts] = 65536 B
    __shared__ short lds_w[32768];

    const int T    = seqlen[0];
    const int tid  = threadIdx.x;
    const int g    = blockIdx.x;
    const int nthr = gridDim.x * blockDim.x;
    const int gtid = g * blockDim.x + tid;

    // ---- cast weights & x to bf16; zero barrier counters ----
    for (int idx = gtid; idx < H * H; idx += nthr) wjh_bf[idx] = __float2bfloat16(Wjh[idx]);
    for (int idx = gtid; idx < H * H; idx += nthr) wkh_bf[idx] = __float2bfloat16(Wkh[idx]);
    for (int idx = gtid; idx < O * H; idx += nthr) wo_bf[idx]  = __float2bfloat16(Wo[idx]);
    for (int idx = gtid; idx < H * I; idx += nthr) wjx_bf[idx] = __float2bfloat16(Wjx[idx]);
    for (int idx = gtid; idx < H * I; idx += nthr) wkx_bf[idx] = __float2bfloat16(Wkx[idx]);
    for (int idx = gtid; idx < B * I; idx += nthr) x_bf[idx]   = __float2bfloat16(x[idx]);
    if (gtid < 8 * 256) cnt[gtid] = 0;

    // ---- geometry ----
    const int w     = tid >> 6;
    const int lane  = tid & 63;
    const int quad  = lane >> 4;
    const int lm    = lane & 15;
    const int iblk  = g & 7;            // XCD-local group id
    const int lblk  = g >> 3;           // 0..63
    const int rbase = iblk * 64 + w * 16;
    const int n0    = lblk * 16;        // gate cols
    const bool has_out = (lblk < 32);
    const int no0   = lblk * 16;        // out cols (valid when has_out)
    int* grp_cnt = cnt + iblk * 256;

    // ---- h0 init: each thread owns 4 (row,col) elements ----
    float hreg[4];
    #pragma unroll
    for (int r = 0; r < 4; ++r) {
        const int row = rbase + quad * 4 + r;
        const int col = n0 + lm;
        const float hv = h0[row * H + col];
        hreg[r] = hv;
        hbf0[row * H + col] = __float2bfloat16(hv);
    }

    cg::this_grid().sync();   // casts + h0 + cnt zero visible device-wide

    // ---- load this WG's Wjh/Wkh rows into LDS (one time) ----
    for (int c = tid; c < 4096; c += 256) {
        const int gate = c >> 11;
        const int cc   = c & 2047;
        const int kb   = cc >> 4;
        const int col  = cc & 15;
        const bf16_t* src = (gate ? wkh_bf : wjh_bf) + (n0 + col) * H + kb * 8;
        *reinterpret_cast<short8*>(&lds_w[c * 8]) = *reinterpret_cast<const short8*>(src);
    }
    __syncthreads();

    // ---- jx/kx (+ all biases) in registers ----
    float jxr[4], kxr[4];
    {
        f32x4 aJ = {0.f, 0.f, 0.f, 0.f};
        f32x4 aK = {0.f, 0.f, 0.f, 0.f};
        const bf16_t* aP = x_bf   + (rbase + lm) * I + quad * 8;
        const bf16_t* jP = wjx_bf + (n0 + lm) * I + quad * 8;
        const bf16_t* kP = wkx_bf + (n0 + lm) * I + quad * 8;
        #pragma unroll 4
        for (int k0 = 0; k0 < I; k0 += 32) {
            short8 a = ldfrag(aP + k0);
            aJ = __builtin_amdgcn_mfma_f32_16x16x32_bf16(a, ldfrag(jP + k0), aJ, 0, 0, 0);
            aK = __builtin_amdgcn_mfma_f32_16x16x32_bf16(a, ldfrag(kP + k0), aK, 0, 0, 0);
        }
        const int col = n0 + lm;
        #pragma unroll
        for (int r = 0; r < 4; ++r) {
            jxr[r] = aJ[r] + bjx[col] + bjh[col];
            kxr[r] = aK[r] + bkx[col] + bkh[col];
        }
    }
    const float bo_v = has_out ? bo[no0 + lm] : 0.0f;

    // ---- recurrence: step t reads h_t, computes h_{t+1} and out_{t-1} ----
    for (int t = 0; t < T; ++t) {
        if (t > 0) group_wait(grp_cnt + t, 64);   // h_t published by all 64 group WGs
        const bf16_t* hb  = (t & 1) ? hbf1 : hbf0;
        bf16_t*       hbn = (t & 1) ? hbf0 : hbf1;

        f32x4 accJ = {0.f, 0.f, 0.f, 0.f};
        f32x4 accK = {0.f, 0.f, 0.f, 0.f};
        f32x4 accO = {0.f, 0.f, 0.f, 0.f};

        const bf16_t* aP = hb    + (rbase + lm) * H + quad * 8;
        const bf16_t* oP = wo_bf + (no0 + lm) * H + quad * 8;
        const short*  jL = lds_w + quad * 128 + lm * 8;          // [kb][col][8]
        const short*  kL = jL + 16384;

        if (has_out) {
            #pragma unroll 4
            for (int k0 = 0; k0 < H; k0 += 32) {
                short8 a  = ldfrag(aP + k0);
                short8 bj = *reinterpret_cast<const short8*>(jL + (k0 >> 3) * 128);
                short8 bk = *reinterpret_cast<const short8*>(kL + (k0 >> 3) * 128);
                accJ = __builtin_amdgcn_mfma_f32_16x16x32_bf16(a, bj, accJ, 0, 0, 0);
                accK = __builtin_amdgcn_mfma_f32_16x16x32_bf16(a, bk, accK, 0, 0, 0);
                accO = __builtin_amdgcn_mfma_f32_16x16x32_bf16(a, ldfrag(oP + k0), accO, 0, 0, 0);
            }
        } else {
            #pragma unroll 4
            for (int k0 = 0; k0 < H; k0 += 32) {
                short8 a  = ldfrag(aP + k0);
                short8 bj = *reinterpret_cast<const short8*>(jL + (k0 >> 3) * 128);
                short8 bk = *reinterpret_cast<const short8*>(kL + (k0 >> 3) * 128);
                accJ = __builtin_amdgcn_mfma_f32_16x16x32_bf16(a, bj, accJ, 0, 0, 0);
                accK = __builtin_amdgcn_mfma_f32_16x16x32_bf16(a, bk, accK, 0, 0, 0);
            }
        }

        if (has_out && t > 0) {
            #pragma unroll
            for (int r = 0; r < 4; ++r) {
                const int row = rbase + quad * 4 + r;
                out[(row * T + (t - 1)) * O + no0 + lm] = accO[r] + bo_v;
            }
        }

        #pragma unroll
        for (int r = 0; r < 4; ++r) {
            const int row = rbase + quad * 4 + r;
            const int col = n0 + lm;
            const float jv = sigmoid_f(accJ[r] + jxr[r]);
            const float kv = sigmoid_f(accK[r] + kxr[r]);
            const float hv = hreg[r];
            const float hn = jv * (1.0f - hv) + (1.0f - kv) * hv;
            hreg[r] = hn;
            hbn[row * H + col] = __float2bfloat16(hn);
        }

        group_post(grp_cnt + t + 1);   // publish h_{t+1}
    }

    group_wait(grp_cnt + T, 64);       // h_T published

    // ---- epilogue: out_{T-1} and h_final ----
    {
        const bf16_t* hb = (T & 1) ? hbf1 : hbf0;
        if (has_out) {
            f32x4 accO = {0.f, 0.f, 0.f, 0.f};
            const bf16_t* aP = hb    + (rbase + lm) * H + quad * 8;
            const bf16_t* oP = wo_bf + (no0 + lm) * H + quad * 8;
            #pragma unroll 4
            for (int k0 = 0; k0 < H; k0 += 32) {
                accO = __builtin_amdgcn_mfma_f32_16x16x32_bf16(ldfrag(aP + k0), ldfrag(oP + k0), accO, 0, 0, 0);
            }
            #pragma unroll
            for (int r = 0; r < 4; ++r) {
                const int row = rbase + quad * 4 + r;
                out[(row * T + (T - 1)) * O + no0 + lm] = accO[r] + bo_v;
            }
        }
        const int hfin = B * T * O;
        #pragma unroll
        for (int r = 0; r < 4; ++r) {
            const int row = rbase + quad * 4 + r;
            const int col = n0 + lm;
            out[hfin + row * H + col] = hreg[r];
        }
    }
}

extern "C" void kernel_launch(void* const* d_in, const int* in_sizes, int n_in,
                              void* d_out, int out_size, void* d_ws, size_t ws_size,
                              hipStream_t stream) {
    const float* x   = (const float*)d_in[0];
    const float* h0  = (const float*)d_in[1];
    const float* Wjx = (const float*)d_in[2];
    const float* bjx = (const float*)d_in[3];
    const float* Wjh = (const float*)d_in[4];
    const float* bjh = (const float*)d_in[5];
    const float* Wkx = (const float*)d_in[6];
    const float* bkx = (const float*)d_in[7];
    const float* Wkh = (const float*)d_in[8];
    const float* bkh = (const float*)d_in[9];
    const float* Wo  = (const float*)d_in[10];
    const float* bo  = (const float*)d_in[11];
    const int* seqlen = (const int*)d_in[12];
    float* out = (float*)d_out;

    // workspace layout (bytes)
    char* ws = (char*)d_ws;
    bf16_t* wjh_bf = (bf16_t*)(ws + 0);                 // 2 MB
    bf16_t* wkh_bf = (bf16_t*)(ws + 2097152);           // 2 MB
    bf16_t* wo_bf  = (bf16_t*)(ws + 4194304);           // 1 MB
    bf16_t* wjx_bf = (bf16_t*)(ws + 5242880);           // 1 MB
    bf16_t* wkx_bf = (bf16_t*)(ws + 6291456);           // 1 MB
    bf16_t* x_bf   = (bf16_t*)(ws + 7340032);           // 0.5 MB
    bf16_t* hbf0   = (bf16_t*)(ws + 7864320);           // 1 MB
    bf16_t* hbf1   = (bf16_t*)(ws + 8912896);           // 1 MB
    int*    cnt    = (int*)   (ws + 9961472);           // 8 KB barrier counters

    void* args[] = {
        &x, &h0, &Wjx, &bjx, &Wjh, &bjh, &Wkx, &bkx, &Wkh, &bkh, &Wo, &bo,
        &seqlen, &out,
        &wjh_bf, &wkh_bf, &wo_bf, &wjx_bf, &wkx_bf, &x_bf, &hbf0, &hbf1, &cnt
    };
    hipLaunchCooperativeKernel((const void*)flipflop_rnn_kernel,
                               dim3(512), dim3(256), args, 0, stream);
}

// Round 10
// 1923.422 us; speedup vs baseline: 1.2128x; 1.0535x over previous
//
#include <hip/hip_runtime.h>
#include <hip/hip_bf16.h>
#include <hip/hip_cooperative_groups.h>

namespace cg = cooperative_groups;

constexpr int B = 512;
constexpr int I = 512;
constexpr int H = 1024;
constexpr int O = 512;

using short8 = __attribute__((ext_vector_type(8))) short;
using f32x4  = __attribute__((ext_vector_type(4))) float;
using bf16_t = __hip_bfloat16;

__device__ __forceinline__ short8 ldfrag(const bf16_t* p) {
    return *reinterpret_cast<const short8*>(p);
}
__device__ __forceinline__ float sigmoid_f(float z) {
    return 1.0f / (1.0f + __expf(-z));
}

// ---- R0 barrier, verbatim (proven across R0/R8/R9) ----
// Evidence log (10 rounds): step ~14.7us INVARIANT to barrier design (x3),
// inv scope (x2), work placement (x2), unroll (x2). Traffic arithmetic:
// gate-GEMM A-operand (h) volume is 32 row-tiles x 64 col-tiles x 32KB =
// 64 MB/step; 64MB/14.7us = 4.4 TB/s = MALL-class service. R2's dead L2-local
// fast path says group WGs are likely NOT co-XCD => h transits the MALL =>
// step = A-volume / MALL-BW, invariant to everything tried. THIS round halves
// A-volume: each wave computes 16 rows x 32 cols (2 B-frags share 1 A-frag).
// LDS 64->128KB (32 gate cols), 256 WGs x 256 thr, 1 WG/CU, group = 32 WGs.
// Gate-loop keeps the EXACT R0 per-chunk interleave (only schedule that ever
// passed); barrier data path byte-identical.
__device__ __forceinline__ void group_wait(int* c, int target) {
    if (threadIdx.x == 0) {
        while (__hip_atomic_load(c, __ATOMIC_RELAXED, __HIP_MEMORY_SCOPE_AGENT) < target)
            __builtin_amdgcn_s_sleep(2);
    }
    __syncthreads();
    asm volatile("buffer_inv" ::: "memory");   // L1 invalidate (R9: == sc0 perf)
}
__device__ __forceinline__ void group_post(int* c) {
    __syncthreads();  // drains this WG's h stores (vmcnt 0)
    if (threadIdx.x == 0)
        __hip_atomic_fetch_add(c, 1, __ATOMIC_RELAXED, __HIP_MEMORY_SCOPE_AGENT);
}

// 256 WGs x 256 thr, 128KB LDS (32 cols of Wjh+Wkh), 1 WG/CU.
// WG(g): iblk = g&7 (64 batch rows), lblk = g>>3 (0..31 -> 32 gate cols).
// lblk<16 WGs additionally compute 32 out cols (Wo streamed, A shared).
__global__ __launch_bounds__(256, 1)
void flipflop_rnn_kernel(const float* __restrict__ x,  const float* __restrict__ h0,
                         const float* __restrict__ Wjx, const float* __restrict__ bjx,
                         const float* __restrict__ Wjh, const float* __restrict__ bjh,
                         const float* __restrict__ Wkx, const float* __restrict__ bkx,
                         const float* __restrict__ Wkh, const float* __restrict__ bkh,
                         const float* __restrict__ Wo,  const float* __restrict__ bo,
                         const int* __restrict__ seqlen,
                         float* __restrict__ out,
                         bf16_t* __restrict__ wjh_bf, bf16_t* __restrict__ wkh_bf,
                         bf16_t* __restrict__ wo_bf,  bf16_t* __restrict__ wjx_bf,
                         bf16_t* __restrict__ wkx_bf, bf16_t* __restrict__ x_bf,
                         bf16_t* __restrict__ hbf0,   bf16_t* __restrict__ hbf1,
                         int* __restrict__ cnt)
{
    // [gate 0/1][kb 0..127][col 0..31][8 shorts] = 131072 B
    __shared__ short lds_w[65536];

    const int T    = seqlen[0];
    const int tid  = threadIdx.x;
    const int g    = blockIdx.x;
    const int nthr = gridDim.x * blockDim.x;   // 65536
    const int gtid = g * blockDim.x + tid;

    // ---- cast weights & x to bf16; zero barrier counters ----
    for (int idx = gtid; idx < H * H; idx += nthr) wjh_bf[idx] = __float2bfloat16(Wjh[idx]);
    for (int idx = gtid; idx < H * H; idx += nthr) wkh_bf[idx] = __float2bfloat16(Wkh[idx]);
    for (int idx = gtid; idx < O * H; idx += nthr) wo_bf[idx]  = __float2bfloat16(Wo[idx]);
    for (int idx = gtid; idx < H * I; idx += nthr) wjx_bf[idx] = __float2bfloat16(Wjx[idx]);
    for (int idx = gtid; idx < H * I; idx += nthr) wkx_bf[idx] = __float2bfloat16(Wkx[idx]);
    for (int idx = gtid; idx < B * I; idx += nthr) x_bf[idx]   = __float2bfloat16(x[idx]);
    if (gtid < 8 * 256) cnt[gtid] = 0;

    // ---- geometry ----
    const int w     = tid >> 6;          // wave 0..3 -> row-tile
    const int lane  = tid & 63;
    const int quad  = lane >> 4;
    const int lm    = lane & 15;
    const int iblk  = g & 7;             // batch-row group (64 rows)
    const int lblk  = g >> 3;            // 0..31 -> 32 gate cols
    const int rbase = iblk * 64 + w * 16;
    const int n0    = lblk * 32;         // gate col base (two 16-col tiles)
    const bool has_out = (lblk < 16);
    const int no0   = lblk * 32;         // out col base (valid when has_out)
    int* grp_cnt = cnt + iblk * 256;

    // ---- h0 init: each thread owns 2 col-tiles x 4 rows ----
    float hreg[2][4];
    #pragma unroll
    for (int ct = 0; ct < 2; ++ct) {
        #pragma unroll
        for (int r = 0; r < 4; ++r) {
            const int row = rbase + quad * 4 + r;
            const int col = n0 + ct * 16 + lm;
            const float hv = h0[row * H + col];
            hreg[ct][r] = hv;
            hbf0[row * H + col] = __float2bfloat16(hv);
        }
    }

    cg::this_grid().sync();   // casts + h0 + cnt zero visible device-wide

    // ---- load this WG's 32 cols of Wjh/Wkh into LDS (one time) ----
    // layout: ((gate*128 + kb)*32 + col)*8 shorts
    for (int c = tid; c < 8192; c += 256) {
        const int gate = c >> 12;
        const int cc   = c & 4095;
        const int kb   = cc >> 5;
        const int col  = cc & 31;
        const bf16_t* src = (gate ? wkh_bf : wjh_bf) + (n0 + col) * H + kb * 8;
        *reinterpret_cast<short8*>(&lds_w[c * 8]) = *reinterpret_cast<const short8*>(src);
    }
    __syncthreads();

    // ---- jx/kx (+ all biases) in registers, both col-tiles ----
    float jxr[2][4], kxr[2][4];
    {
        f32x4 aJ0 = {0.f,0.f,0.f,0.f}, aJ1 = {0.f,0.f,0.f,0.f};
        f32x4 aK0 = {0.f,0.f,0.f,0.f}, aK1 = {0.f,0.f,0.f,0.f};
        const bf16_t* aP  = x_bf   + (rbase + lm) * I + quad * 8;
        const bf16_t* jP0 = wjx_bf + (n0 + lm) * I + quad * 8;
        const bf16_t* jP1 = jP0 + 16 * I;
        const bf16_t* kP0 = wkx_bf + (n0 + lm) * I + quad * 8;
        const bf16_t* kP1 = kP0 + 16 * I;
        #pragma unroll 4
        for (int k0 = 0; k0 < I; k0 += 32) {
            short8 a = ldfrag(aP + k0);
            aJ0 = __builtin_amdgcn_mfma_f32_16x16x32_bf16(a, ldfrag(jP0 + k0), aJ0, 0, 0, 0);
            aJ1 = __builtin_amdgcn_mfma_f32_16x16x32_bf16(a, ldfrag(jP1 + k0), aJ1, 0, 0, 0);
            aK0 = __builtin_amdgcn_mfma_f32_16x16x32_bf16(a, ldfrag(kP0 + k0), aK0, 0, 0, 0);
            aK1 = __builtin_amdgcn_mfma_f32_16x16x32_bf16(a, ldfrag(kP1 + k0), aK1, 0, 0, 0);
        }
        #pragma unroll
        for (int r = 0; r < 4; ++r) {
            const int c0 = n0 + lm, c1 = n0 + 16 + lm;
            jxr[0][r] = aJ0[r] + bjx[c0] + bjh[c0];
            jxr[1][r] = aJ1[r] + bjx[c1] + bjh[c1];
            kxr[0][r] = aK0[r] + bkx[c0] + bkh[c0];
            kxr[1][r] = aK1[r] + bkx[c1] + bkh[c1];
        }
    }
    const float bo_v0 = has_out ? bo[no0 + lm]      : 0.0f;
    const float bo_v1 = has_out ? bo[no0 + 16 + lm] : 0.0f;

    // ---- recurrence: step t reads h_t, computes h_{t+1} and out_{t-1} ----
    for (int t = 0; t < T; ++t) {
        if (t > 0) group_wait(grp_cnt + t, 32);   // h_t published by all 32 group WGs
        const bf16_t* hb  = (t & 1) ? hbf1 : hbf0;
        bf16_t*       hbn = (t & 1) ? hbf0 : hbf1;

        f32x4 accJ0 = {0.f,0.f,0.f,0.f}, accJ1 = {0.f,0.f,0.f,0.f};
        f32x4 accK0 = {0.f,0.f,0.f,0.f}, accK1 = {0.f,0.f,0.f,0.f};
        f32x4 accO0 = {0.f,0.f,0.f,0.f}, accO1 = {0.f,0.f,0.f,0.f};

        const bf16_t* aP  = hb    + (rbase + lm) * H + quad * 8;
        const bf16_t* oP0 = wo_bf + (no0 + lm) * H + quad * 8;
        const bf16_t* oP1 = oP0 + 16 * H;
        const short*  jL  = lds_w + quad * 256 + lm * 8;   // ((kb)*32+col)*8
        const short*  kL  = jL + 32768;

        // R0-pattern interleave, widened: 1 A-load feeds 4 (6) MFMAs
        if (has_out) {
            #pragma unroll 4
            for (int k0 = 0; k0 < H; k0 += 32) {
                short8 a   = ldfrag(aP + k0);
                const short* Lj = jL + (k0 >> 3) * 256;
                const short* Lk = kL + (k0 >> 3) * 256;
                short8 bj0 = *reinterpret_cast<const short8*>(Lj);
                short8 bj1 = *reinterpret_cast<const short8*>(Lj + 128);
                short8 bk0 = *reinterpret_cast<const short8*>(Lk);
                short8 bk1 = *reinterpret_cast<const short8*>(Lk + 128);
                accJ0 = __builtin_amdgcn_mfma_f32_16x16x32_bf16(a, bj0, accJ0, 0, 0, 0);
                accJ1 = __builtin_amdgcn_mfma_f32_16x16x32_bf16(a, bj1, accJ1, 0, 0, 0);
                accK0 = __builtin_amdgcn_mfma_f32_16x16x32_bf16(a, bk0, accK0, 0, 0, 0);
                accK1 = __builtin_amdgcn_mfma_f32_16x16x32_bf16(a, bk1, accK1, 0, 0, 0);
                accO0 = __builtin_amdgcn_mfma_f32_16x16x32_bf16(a, ldfrag(oP0 + k0), accO0, 0, 0, 0);
                accO1 = __builtin_amdgcn_mfma_f32_16x16x32_bf16(a, ldfrag(oP1 + k0), accO1, 0, 0, 0);
            }
        } else {
            #pragma unroll 4
            for (int k0 = 0; k0 < H; k0 += 32) {
                short8 a   = ldfrag(aP + k0);
                const short* Lj = jL + (k0 >> 3) * 256;
                const short* Lk = kL + (k0 >> 3) * 256;
                short8 bj0 = *reinterpret_cast<const short8*>(Lj);
                short8 bj1 = *reinterpret_cast<const short8*>(Lj + 128);
                short8 bk0 = *reinterpret_cast<const short8*>(Lk);
                short8 bk1 = *reinterpret_cast<const short8*>(Lk + 128);
                accJ0 = __builtin_amdgcn_mfma_f32_16x16x32_bf16(a, bj0, accJ0, 0, 0, 0);
                accJ1 = __builtin_amdgcn_mfma_f32_16x16x32_bf16(a, bj1, accJ1, 0, 0, 0);
                accK0 = __builtin_amdgcn_mfma_f32_16x16x32_bf16(a, bk0, accK0, 0, 0, 0);
                accK1 = __builtin_amdgcn_mfma_f32_16x16x32_bf16(a, bk1, accK1, 0, 0, 0);
            }
        }

        if (has_out && t > 0) {
            #pragma unroll
            for (int r = 0; r < 4; ++r) {
                const int row = rbase + quad * 4 + r;
                out[(row * T + (t - 1)) * O + no0 + lm]      = accO0[r] + bo_v0;
                out[(row * T + (t - 1)) * O + no0 + 16 + lm] = accO1[r] + bo_v1;
            }
        }

        #pragma unroll
        for (int r = 0; r < 4; ++r) {
            const int row = rbase + quad * 4 + r;
            {
                const float jv = sigmoid_f(accJ0[r] + jxr[0][r]);
                const float kv = sigmoid_f(accK0[r] + kxr[0][r]);
                const float hv = hreg[0][r];
                const float hn = jv * (1.0f - hv) + (1.0f - kv) * hv;
                hreg[0][r] = hn;
                hbn[row * H + n0 + lm] = __float2bfloat16(hn);
            }
            {
                const float jv = sigmoid_f(accJ1[r] + jxr[1][r]);
                const float kv = sigmoid_f(accK1[r] + kxr[1][r]);
                const float hv = hreg[1][r];
                const float hn = jv * (1.0f - hv) + (1.0f - kv) * hv;
                hreg[1][r] = hn;
                hbn[row * H + n0 + 16 + lm] = __float2bfloat16(hn);
            }
        }

        group_post(grp_cnt + t + 1);   // publish h_{t+1}
    }

    group_wait(grp_cnt + T, 32);       // h_T published

    // ---- epilogue: out_{T-1} and h_final ----
    {
        const bf16_t* hb = (T & 1) ? hbf1 : hbf0;
        if (has_out) {
            f32x4 accO0 = {0.f,0.f,0.f,0.f}, accO1 = {0.f,0.f,0.f,0.f};
            const bf16_t* aP  = hb    + (rbase + lm) * H + quad * 8;
            const bf16_t* oP0 = wo_bf + (no0 + lm) * H + quad * 8;
            const bf16_t* oP1 = oP0 + 16 * H;
            #pragma unroll 4
            for (int k0 = 0; k0 < H; k0 += 32) {
                short8 a = ldfrag(aP + k0);
                accO0 = __builtin_amdgcn_mfma_f32_16x16x32_bf16(a, ldfrag(oP0 + k0), accO0, 0, 0, 0);
                accO1 = __builtin_amdgcn_mfma_f32_16x16x32_bf16(a, ldfrag(oP1 + k0), accO1, 0, 0, 0);
            }
            #pragma unroll
            for (int r = 0; r < 4; ++r) {
                const int row = rbase + quad * 4 + r;
                out[(row * T + (T - 1)) * O + no0 + lm]      = accO0[r] + bo_v0;
                out[(row * T + (T - 1)) * O + no0 + 16 + lm] = accO1[r] + bo_v1;
            }
        }
        const int hfin = B * T * O;
        #pragma unroll
        for (int r = 0; r < 4; ++r) {
            const int row = rbase + quad * 4 + r;
            out[hfin + row * H + n0 + lm]      = hreg[0][r];
            out[hfin + row * H + n0 + 16 + lm] = hreg[1][r];
        }
    }
}

extern "C" void kernel_launch(void* const* d_in, const int* in_sizes, int n_in,
                              void* d_out, int out_size, void* d_ws, size_t ws_size,
                              hipStream_t stream) {
    const float* x   = (const float*)d_in[0];
    const float* h0  = (const float*)d_in[1];
    const float* Wjx = (const float*)d_in[2];
    const float* bjx = (const float*)d_in[3];
    const float* Wjh = (const float*)d_in[4];
    const float* bjh = (const float*)d_in[5];
    const float* Wkx = (const float*)d_in[6];
    const float* bkx = (const float*)d_in[7];
    const float* Wkh = (const float*)d_in[8];
    const float* bkh = (const float*)d_in[9];
    const float* Wo  = (const float*)d_in[10];
    const float* bo  = (const float*)d_in[11];
    const int* seqlen = (const int*)d_in[12];
    float* out = (float*)d_out;

    // workspace layout (bytes)
    char* ws = (char*)d_ws;
    bf16_t* wjh_bf = (bf16_t*)(ws + 0);                 // 2 MB
    bf16_t* wkh_bf = (bf16_t*)(ws + 2097152);           // 2 MB
    bf16_t* wo_bf  = (bf16_t*)(ws + 4194304);           // 1 MB
    bf16_t* wjx_bf = (bf16_t*)(ws + 5242880);           // 1 MB
    bf16_t* wkx_bf = (bf16_t*)(ws + 6291456);           // 1 MB
    bf16_t* x_bf   = (bf16_t*)(ws + 7340032);           // 0.5 MB
    bf16_t* hbf0   = (bf16_t*)(ws + 7864320);           // 1 MB
    bf16_t* hbf1   = (bf16_t*)(ws + 8912896);           // 1 MB
    int*    cnt    = (int*)   (ws + 9961472);           // 8 KB barrier counters

    void* args[] = {
        &x, &h0, &Wjx, &bjx, &Wjh, &bjh, &Wkx, &bkx, &Wkh, &bkh, &Wo, &bo,
        &seqlen, &out,
        &wjh_bf, &wkh_bf, &wo_bf, &wjx_bf, &wkx_bf, &x_bf, &hbf0, &hbf1, &cnt
    };
    hipLaunchCooperativeKernel((const void*)flipflop_rnn_kernel,
                               dim3(256), dim3(256), args, 0, stream);
}